// Round 4
// baseline (767.644 us; speedup 1.0000x reference)
//
#include <hip/hip_runtime.h>
#include <stdint.h>

#define BB 4
#define NN 2048
#define DIN 128
#define DOUT 32
#define HH 8
#define NW 64   // u32 bitmask words per adjacency row

typedef __bf16 bf16x8 __attribute__((ext_vector_type(8)));
typedef float  f32x4  __attribute__((ext_vector_type(4)));

static __device__ __forceinline__ unsigned short f2b(float f) {
    __bf16 h = (__bf16)f;
    return __builtin_bit_cast(unsigned short, h);
}

// ---------------------------------------------------------------------------
// K1: WhT[b][h][d][n] (bf16) = sum_i H[b][n][i] * W[h][i][d]   (fp32 inputs)
// Fused epilogue: E[b][h][n] = exp( sum_d Wh[n][d] * a2[h][d] )
// ---------------------------------------------------------------------------
__global__ __launch_bounds__(256) void k_wht(const float* __restrict__ Hg,
                                             const float* __restrict__ Wg,
                                             const float* __restrict__ ag,
                                             unsigned short* __restrict__ WhT,
                                             float* __restrict__ E)
{
    __shared__ float Hs[DIN * 16];          // [i][n] transposed tile, 8 KB
    __shared__ float ejred[HH][16][36];     // ej partials
    const int t  = threadIdx.x;
    const int b  = blockIdx.x >> 7;
    const int n0 = (blockIdx.x & 127) << 4;

    {   // stage H tile transposed: each thread loads 8 contiguous fp32 along i
        const int r = t >> 4, i0 = (t & 15) << 3;
        const float4* hp = (const float4*)(Hg + ((size_t)(b * NN + n0 + r)) * DIN + i0);
        float4 u0 = hp[0], u1 = hp[1];
        float vv[8] = { u0.x, u0.y, u0.z, u0.w, u1.x, u1.y, u1.z, u1.w };
#pragma unroll
        for (int j = 0; j < 8; j++) Hs[(i0 + j) * 16 + r] = vv[j];
    }
    __syncthreads();

    const int h = t >> 5, d = t & 31;
    f32x4 a0 = {0,0,0,0}, a1 = {0,0,0,0}, a2 = {0,0,0,0}, a3 = {0,0,0,0};
    const float* wp = Wg + h * DIN * DOUT + d;
#pragma unroll 8
    for (int i = 0; i < DIN; i++) {
        float wv = wp[i * DOUT];
        const f32x4* hr = (const f32x4*)&Hs[i * 16];   // wave-broadcast reads
        a0 += wv * hr[0];
        a1 += wv * hr[1];
        a2 += wv * hr[2];
        a3 += wv * hr[3];
    }
    float v[16] = { a0[0],a0[1],a0[2],a0[3], a1[0],a1[1],a1[2],a1[3],
                    a2[0],a2[1],a2[2],a2[3], a3[0],a3[1],a3[2],a3[3] };
    unsigned int pw[8];
#pragma unroll
    for (int j = 0; j < 8; j++)
        pw[j] = (unsigned int)f2b(v[2*j]) | ((unsigned int)f2b(v[2*j+1]) << 16);
    uint4* dst = (uint4*)(WhT + ((size_t)((b * HH + h) * DOUT + d)) * NN + n0);
    dst[0] = make_uint4(pw[0], pw[1], pw[2], pw[3]);
    dst[1] = make_uint4(pw[4], pw[5], pw[6], pw[7]);

    // ---- fused k_e: ej partial per (h,d), reduce over d via LDS ----
    const float a2v = ag[h * 2 * DOUT + DOUT + d];
#pragma unroll
    for (int j = 0; j < 16; j++) ejred[h][j][d] = v[j] * a2v;
    __syncthreads();
    if (t < 128) {
        const int hh = t >> 4, j = t & 15;
        const f32x4* rp = (const f32x4*)&ejred[hh][j][0];
        f32x4 s4 = rp[0] + rp[1] + rp[2] + rp[3] + rp[4] + rp[5] + rp[6] + rp[7];
        float s = s4[0] + s4[1] + s4[2] + s4[3];
        E[((size_t)(b * HH + hh)) * NN + n0 + j] = __expf(s);
    }
}

// ---------------------------------------------------------------------------
// K_bits: pack adj (int32 0/1) into bitmask via ballot
// ---------------------------------------------------------------------------
__global__ __launch_bounds__(256) void k_bits(const int* __restrict__ adj,
                                              unsigned long long* __restrict__ BM)
{
    size_t tg = (size_t)blockIdx.x * 256 + threadIdx.x;   // < 16,777,216
    unsigned long long m = __ballot(adj[tg] != 0);
    if ((threadIdx.x & 63) == 0) BM[tg >> 6] = m;
}

// ---------------------------------------------------------------------------
// K3: unchanged from round 3. Launched TWICE this round (idempotent:
// reads E/BM/WhT only, writes out0/out1 deterministically) purely to
// measure T(k_main) = new_total - 642 us, since the top-5 counter table
// is saturated by the harness poison fills and cannot show it.
// ---------------------------------------------------------------------------
__global__ __launch_bounds__(256) void k_main(const float* __restrict__ E,
                                              const unsigned int* __restrict__ BM,
                                              const unsigned short* __restrict__ WhT,
                                              float* __restrict__ out0,
                                              float* __restrict__ out1)
{
    __shared__ __align__(16) char smem[12608];
    float*        Es   = (float*)smem;                              // 8192 B
    unsigned int (*bits)[68] = (unsigned int (*)[68])(smem + 8192); // 4352 B
    float*        invS = (float*)(smem + 8192 + 4352);              // 64 B
    float (*Cred)[16][33] = (float (*)[16][33])smem;                // 8448 B overlay

    const int t   = threadIdx.x;
    // bijective swizzle: 4096 blocks = 8 xcd * 4 bh * 128 tiles
    const int xcd = blockIdx.x & 7;
    const int jx  = blockIdx.x >> 3;           // 0..511
    const int bh  = (xcd << 2) + (jx >> 7);
    const int b   = bh >> 3, h = bh & 7;
    const int n0  = (jx & 127) << 4;

    const int w = t >> 6, lane = t & 63;
    const int quad = lane >> 4, l16 = lane & 15;   // MFMA fragment mapping

    // ---- hoisted chunk-0 B prefetch (latency hides under phases 0-1) ----
    const unsigned short* wB0 = WhT + ((size_t)(bh * DOUT) + l16) * NN;   // d = l16
    const unsigned short* wB1 = wB0 + (size_t)16 * NN;                    // d = l16+16
    const int mA0 = (w << 9) + (quad << 3);
    uint4 B00 = *(const uint4*)(wB0 + mA0);
    uint4 B01 = *(const uint4*)(wB0 + mA0 + 32);
    uint4 B10 = *(const uint4*)(wB1 + mA0);
    uint4 B11 = *(const uint4*)(wB1 + mA0 + 32);

    // ---- phase 0: stage E row and 16 bitmask rows ----
    {
        const f32x4* src = (const f32x4*)(E + (size_t)bh * NN);
        f32x4* dst = (f32x4*)Es;
        dst[t]       = src[t];
        dst[t + 256] = src[t + 256];
        const int r = t >> 4, w0 = (t & 15) << 2;
        *(uint4*)&bits[r][w0] =
            *(const uint4*)(BM + ((size_t)(b * NN + n0 + r)) * NW + w0);
    }
    __syncthreads();

    // ---- phase 1: S_r = sum over set bits of E[m]; shfl butterfly reduce ----
    {
        const int r = t >> 4, l = t & 15;
        const unsigned int* br = bits[r];
        float s = 0.f;
#pragma unroll 4
        for (int k2 = 0; k2 < NW; k2++) {
            unsigned int wd = br[k2];
            int m = (k2 << 5) + l;
            float v0 = Es[m], v1 = Es[m + 16];   // unconditional LDS reads
            s += ((wd >> l) & 1)        ? v0 : 0.f;
            s += ((wd >> (l + 16)) & 1) ? v1 : 0.f;
        }
        // 16 threads of row r are contiguous lanes of one wave
        s += __shfl_xor(s, 1, 16);
        s += __shfl_xor(s, 2, 16);
        s += __shfl_xor(s, 4, 16);
        s += __shfl_xor(s, 8, 16);
        if (l == 0) invS[r] = 1.0f / s;
    }
    __syncthreads();

    // ---- phase 2: software-pipelined chunks of 64 m; A-frag in regs ----
    f32x4 acc0 = {0,0,0,0}, acc1 = {0,0,0,0};
    const float iv = invS[l16];
    float* o1 = out1 + ((size_t)bh * NN + n0 + l16) * NN;   // alpha row n0+l16

#pragma unroll
    for (int c = 0; c < 8; c++) {
        const int m0 = (w << 9) + (c << 6);
        const int mA = m0 + (quad << 3);

        // prefetch next chunk's B-frags (L2-resident WhT)
        uint4 N00, N01, N10, N11;
        if (c < 7) {
            N00 = *(const uint4*)(wB0 + mA + 64);
            N01 = *(const uint4*)(wB0 + mA + 96);
            N10 = *(const uint4*)(wB1 + mA + 64);
            N11 = *(const uint4*)(wB1 + mA + 96);
        }

        // two mask words covering m0..m0+63 for row l16
        const uint2 bw = *(const uint2*)&bits[l16][m0 >> 5];
        const unsigned int b0 = bw.x >> (quad << 3);   // ks=0  window
        const unsigned int b1 = bw.y >> (quad << 3);   // ks=32 window

        f32x4 e0 = *(const f32x4*)&Es[mA];
        f32x4 e1 = *(const f32x4*)&Es[mA + 4];
        f32x4 e2 = *(const f32x4*)&Es[mA + 32];
        f32x4 e3 = *(const f32x4*)&Es[mA + 36];
        f32x4 x0, x1, x2, x3;
#pragma unroll
        for (int jj = 0; jj < 4; jj++) {
            x0[jj] = ((b0 >> jj) & 1)       ? e0[jj] * iv : 0.f;
            x1[jj] = ((b0 >> (jj + 4)) & 1) ? e1[jj] * iv : 0.f;
            x2[jj] = ((b1 >> jj) & 1)       ? e2[jj] * iv : 0.f;
            x3[jj] = ((b1 >> (jj + 4)) & 1) ? e3[jj] * iv : 0.f;
        }

        // pack A-frags (already in fragment layout: row=l16, k=quad*8+j)
        unsigned int pk[8] = {
            (unsigned int)f2b(x0[0]) | ((unsigned int)f2b(x0[1]) << 16),
            (unsigned int)f2b(x0[2]) | ((unsigned int)f2b(x0[3]) << 16),
            (unsigned int)f2b(x1[0]) | ((unsigned int)f2b(x1[1]) << 16),
            (unsigned int)f2b(x1[2]) | ((unsigned int)f2b(x1[3]) << 16),
            (unsigned int)f2b(x2[0]) | ((unsigned int)f2b(x2[1]) << 16),
            (unsigned int)f2b(x2[2]) | ((unsigned int)f2b(x2[3]) << 16),
            (unsigned int)f2b(x3[0]) | ((unsigned int)f2b(x3[1]) << 16),
            (unsigned int)f2b(x3[2]) | ((unsigned int)f2b(x3[3]) << 16) };
        bf16x8 af0 = __builtin_bit_cast(bf16x8, make_uint4(pk[0], pk[1], pk[2], pk[3]));
        bf16x8 af1 = __builtin_bit_cast(bf16x8, make_uint4(pk[4], pk[5], pk[6], pk[7]));

        // MFMA with current (prefetched) B-frags
        acc0 = __builtin_amdgcn_mfma_f32_16x16x32_bf16(af0, __builtin_bit_cast(bf16x8, B00), acc0, 0, 0, 0);
        acc1 = __builtin_amdgcn_mfma_f32_16x16x32_bf16(af0, __builtin_bit_cast(bf16x8, B10), acc1, 0, 0, 0);
        acc0 = __builtin_amdgcn_mfma_f32_16x16x32_bf16(af1, __builtin_bit_cast(bf16x8, B01), acc0, 0, 0, 0);
        acc1 = __builtin_amdgcn_mfma_f32_16x16x32_bf16(af1, __builtin_bit_cast(bf16x8, B11), acc1, 0, 0, 0);

        // alpha fp32 out — after MFMA so store drain decouples from load wait
        *(f32x4*)(o1 + mA)      = x0;
        *(f32x4*)(o1 + mA + 4)  = x1;
        *(f32x4*)(o1 + mA + 32) = x2;
        *(f32x4*)(o1 + mA + 36) = x3;

        if (c < 7) { B00 = N00; B01 = N01; B10 = N10; B11 = N11; }
    }

    // ---- cross-wave C reduction + relu epilogue (Cred overlays Es/bits) ----
    __syncthreads();   // all waves done reading Es/bits before overlay write
#pragma unroll
    for (int i = 0; i < 4; i++) {
        Cred[w][(quad << 2) + i][l16]      = acc0[i];
        Cred[w][(quad << 2) + i][l16 + 16] = acc1[i];
    }
    __syncthreads();
#pragma unroll
    for (int e = t; e < 512; e += 256) {
        const int r = e >> 5, d = e & 31;
        float v = Cred[0][r][d] + Cred[1][r][d] + Cred[2][r][d] + Cred[3][r][d];
        out0[((size_t)(b * NN + n0 + r)) * (HH * DOUT) + h * DOUT + d] = fmaxf(v, 0.f);
    }
}

// ---------------------------------------------------------------------------
extern "C" void kernel_launch(void* const* d_in, const int* in_sizes, int n_in,
                              void* d_out, int out_size, void* d_ws, size_t ws_size,
                              hipStream_t stream)
{
    const float* Hg  = (const float*)d_in[0];
    const int*   adj = (const int*)d_in[1];
    const float* Wg  = (const float*)d_in[2];
    const float* ag  = (const float*)d_in[3];

    float* out0 = (float*)d_out;
    float* out1 = out0 + (size_t)BB * NN * HH * DOUT;   // alpha after h'

    char* ws = (char*)d_ws;
    unsigned short* WhT = (unsigned short*)ws;                                // 4 MB bf16
    float*          E   = (float*)(ws + (size_t)BB*HH*DOUT*NN*2);             // 256 KB
    unsigned int*   BM  = (unsigned int*)(ws + (size_t)BB*HH*DOUT*NN*2
                                             + (size_t)BB*HH*NN*4);           // 2 MB

    k_wht <<<BB * (NN/16),         256, 0, stream>>>(Hg, Wg, ag, WhT, E);
    k_bits<<<(BB * NN * NN) / 256, 256, 0, stream>>>(adj, (unsigned long long*)BM);
    // MEASUREMENT: k_main launched twice (idempotent). T(k_main) = dur_us - 642.
    k_main<<<BB * HH * (NN/16),    256, 0, stream>>>(E, BM, WhT, out0, out1);
    k_main<<<BB * HH * (NN/16),    256, 0, stream>>>(E, BM, WhT, out0, out1);
}

// Round 5
// 624.278 us; speedup vs baseline: 1.2297x; 1.2297x over previous
//
#include <hip/hip_runtime.h>
#include <stdint.h>

#define BB 4
#define NN 2048
#define DIN 128
#define DOUT 32
#define HH 8
#define NW 64   // u32 bitmask words per adjacency row

typedef __bf16 bf16x8 __attribute__((ext_vector_type(8)));
typedef float  f32x4  __attribute__((ext_vector_type(4)));

static __device__ __forceinline__ unsigned short f2b(float f) {
    __bf16 h = (__bf16)f;
    return __builtin_bit_cast(unsigned short, h);
}

// ---------------------------------------------------------------------------
// K1: WhT[b][h][d][n] (bf16) = sum_i H[b][n][i] * W[h][i][d]   (fp32 inputs)
// Fused epilogue: E[b][h][n] = exp( sum_d Wh[n][d] * a2[h][d] )
// ---------------------------------------------------------------------------
__global__ __launch_bounds__(256) void k_wht(const float* __restrict__ Hg,
                                             const float* __restrict__ Wg,
                                             const float* __restrict__ ag,
                                             unsigned short* __restrict__ WhT,
                                             float* __restrict__ E)
{
    __shared__ float Hs[DIN * 16];          // [i][n] transposed tile, 8 KB
    __shared__ float ejred[HH][16][36];     // ej partials
    const int t  = threadIdx.x;
    const int b  = blockIdx.x >> 7;
    const int n0 = (blockIdx.x & 127) << 4;

    {   // stage H tile transposed: each thread loads 8 contiguous fp32 along i
        const int r = t >> 4, i0 = (t & 15) << 3;
        const float4* hp = (const float4*)(Hg + ((size_t)(b * NN + n0 + r)) * DIN + i0);
        float4 u0 = hp[0], u1 = hp[1];
        float vv[8] = { u0.x, u0.y, u0.z, u0.w, u1.x, u1.y, u1.z, u1.w };
#pragma unroll
        for (int j = 0; j < 8; j++) Hs[(i0 + j) * 16 + r] = vv[j];
    }
    __syncthreads();

    const int h = t >> 5, d = t & 31;
    f32x4 a0 = {0,0,0,0}, a1 = {0,0,0,0}, a2 = {0,0,0,0}, a3 = {0,0,0,0};
    const float* wp = Wg + h * DIN * DOUT + d;
#pragma unroll 8
    for (int i = 0; i < DIN; i++) {
        float wv = wp[i * DOUT];
        const f32x4* hr = (const f32x4*)&Hs[i * 16];   // wave-broadcast reads
        a0 += wv * hr[0];
        a1 += wv * hr[1];
        a2 += wv * hr[2];
        a3 += wv * hr[3];
    }
    float v[16] = { a0[0],a0[1],a0[2],a0[3], a1[0],a1[1],a1[2],a1[3],
                    a2[0],a2[1],a2[2],a2[3], a3[0],a3[1],a3[2],a3[3] };
    unsigned int pw[8];
#pragma unroll
    for (int j = 0; j < 8; j++)
        pw[j] = (unsigned int)f2b(v[2*j]) | ((unsigned int)f2b(v[2*j+1]) << 16);
    uint4* dst = (uint4*)(WhT + ((size_t)((b * HH + h) * DOUT + d)) * NN + n0);
    dst[0] = make_uint4(pw[0], pw[1], pw[2], pw[3]);
    dst[1] = make_uint4(pw[4], pw[5], pw[6], pw[7]);

    // ---- fused k_e: ej partial per (h,d), reduce over d via LDS ----
    const float a2v = ag[h * 2 * DOUT + DOUT + d];
#pragma unroll
    for (int j = 0; j < 16; j++) ejred[h][j][d] = v[j] * a2v;
    __syncthreads();
    if (t < 128) {
        const int hh = t >> 4, j = t & 15;
        const f32x4* rp = (const f32x4*)&ejred[hh][j][0];
        f32x4 s4 = rp[0] + rp[1] + rp[2] + rp[3] + rp[4] + rp[5] + rp[6] + rp[7];
        float s = s4[0] + s4[1] + s4[2] + s4[3];
        E[((size_t)(b * HH + hh)) * NN + n0 + j] = __expf(s);
    }
}

// ---------------------------------------------------------------------------
// K_bits v2: grid-stride ballot pack. Round-4 decomposition left ~170 us
// unexplained outside k_main(125)/k_wht(~5); old k_bits launched 65,536
// tiny workgroups (262,144 waves, 1 outstanding load each) — launch/latency
// bound. v2: 4,096 workgroups, 16 independent coalesced loads per thread
// (16-deep MLP after unroll). Bit layout identical: u64 word g>>6, bit g&63.
// ---------------------------------------------------------------------------
__global__ __launch_bounds__(256) void k_bits(const int* __restrict__ adj,
                                              unsigned long long* __restrict__ BM)
{
    const size_t base = (size_t)blockIdx.x * 4096 + threadIdx.x;
#pragma unroll
    for (int it = 0; it < 16; it++) {
        size_t g = base + (size_t)(it * 256);
        unsigned long long m = __ballot(adj[g] != 0);
        if ((threadIdx.x & 63) == 0) BM[g >> 6] = m;
    }
}

// ---------------------------------------------------------------------------
// K3: unchanged from round 3 (measured 125 us standalone, ~floor given the
// mandatory 520 MB fp32 output stream). Single launch restored.
// ---------------------------------------------------------------------------
__global__ __launch_bounds__(256) void k_main(const float* __restrict__ E,
                                              const unsigned int* __restrict__ BM,
                                              const unsigned short* __restrict__ WhT,
                                              float* __restrict__ out0,
                                              float* __restrict__ out1)
{
    __shared__ __align__(16) char smem[12608];
    float*        Es   = (float*)smem;                              // 8192 B
    unsigned int (*bits)[68] = (unsigned int (*)[68])(smem + 8192); // 4352 B
    float*        invS = (float*)(smem + 8192 + 4352);              // 64 B
    float (*Cred)[16][33] = (float (*)[16][33])smem;                // 8448 B overlay

    const int t   = threadIdx.x;
    // bijective swizzle: 4096 blocks = 8 xcd * 4 bh * 128 tiles
    const int xcd = blockIdx.x & 7;
    const int jx  = blockIdx.x >> 3;           // 0..511
    const int bh  = (xcd << 2) + (jx >> 7);
    const int b   = bh >> 3, h = bh & 7;
    const int n0  = (jx & 127) << 4;

    const int w = t >> 6, lane = t & 63;
    const int quad = lane >> 4, l16 = lane & 15;   // MFMA fragment mapping

    // ---- hoisted chunk-0 B prefetch (latency hides under phases 0-1) ----
    const unsigned short* wB0 = WhT + ((size_t)(bh * DOUT) + l16) * NN;   // d = l16
    const unsigned short* wB1 = wB0 + (size_t)16 * NN;                    // d = l16+16
    const int mA0 = (w << 9) + (quad << 3);
    uint4 B00 = *(const uint4*)(wB0 + mA0);
    uint4 B01 = *(const uint4*)(wB0 + mA0 + 32);
    uint4 B10 = *(const uint4*)(wB1 + mA0);
    uint4 B11 = *(const uint4*)(wB1 + mA0 + 32);

    // ---- phase 0: stage E row and 16 bitmask rows ----
    {
        const f32x4* src = (const f32x4*)(E + (size_t)bh * NN);
        f32x4* dst = (f32x4*)Es;
        dst[t]       = src[t];
        dst[t + 256] = src[t + 256];
        const int r = t >> 4, w0 = (t & 15) << 2;
        *(uint4*)&bits[r][w0] =
            *(const uint4*)(BM + ((size_t)(b * NN + n0 + r)) * NW + w0);
    }
    __syncthreads();

    // ---- phase 1: S_r = sum over set bits of E[m]; shfl butterfly reduce ----
    {
        const int r = t >> 4, l = t & 15;
        const unsigned int* br = bits[r];
        float s = 0.f;
#pragma unroll 4
        for (int k2 = 0; k2 < NW; k2++) {
            unsigned int wd = br[k2];
            int m = (k2 << 5) + l;
            float v0 = Es[m], v1 = Es[m + 16];   // unconditional LDS reads
            s += ((wd >> l) & 1)        ? v0 : 0.f;
            s += ((wd >> (l + 16)) & 1) ? v1 : 0.f;
        }
        // 16 threads of row r are contiguous lanes of one wave
        s += __shfl_xor(s, 1, 16);
        s += __shfl_xor(s, 2, 16);
        s += __shfl_xor(s, 4, 16);
        s += __shfl_xor(s, 8, 16);
        if (l == 0) invS[r] = 1.0f / s;
    }
    __syncthreads();

    // ---- phase 2: software-pipelined chunks of 64 m; A-frag in regs ----
    f32x4 acc0 = {0,0,0,0}, acc1 = {0,0,0,0};
    const float iv = invS[l16];
    float* o1 = out1 + ((size_t)bh * NN + n0 + l16) * NN;   // alpha row n0+l16

#pragma unroll
    for (int c = 0; c < 8; c++) {
        const int m0 = (w << 9) + (c << 6);
        const int mA = m0 + (quad << 3);

        // prefetch next chunk's B-frags (L2-resident WhT)
        uint4 N00, N01, N10, N11;
        if (c < 7) {
            N00 = *(const uint4*)(wB0 + mA + 64);
            N01 = *(const uint4*)(wB0 + mA + 96);
            N10 = *(const uint4*)(wB1 + mA + 64);
            N11 = *(const uint4*)(wB1 + mA + 96);
        }

        // two mask words covering m0..m0+63 for row l16
        const uint2 bw = *(const uint2*)&bits[l16][m0 >> 5];
        const unsigned int b0 = bw.x >> (quad << 3);   // ks=0  window
        const unsigned int b1 = bw.y >> (quad << 3);   // ks=32 window

        f32x4 e0 = *(const f32x4*)&Es[mA];
        f32x4 e1 = *(const f32x4*)&Es[mA + 4];
        f32x4 e2 = *(const f32x4*)&Es[mA + 32];
        f32x4 e3 = *(const f32x4*)&Es[mA + 36];
        f32x4 x0, x1, x2, x3;
#pragma unroll
        for (int jj = 0; jj < 4; jj++) {
            x0[jj] = ((b0 >> jj) & 1)       ? e0[jj] * iv : 0.f;
            x1[jj] = ((b0 >> (jj + 4)) & 1) ? e1[jj] * iv : 0.f;
            x2[jj] = ((b1 >> jj) & 1)       ? e2[jj] * iv : 0.f;
            x3[jj] = ((b1 >> (jj + 4)) & 1) ? e3[jj] * iv : 0.f;
        }

        // pack A-frags (already in fragment layout: row=l16, k=quad*8+j)
        unsigned int pk[8] = {
            (unsigned int)f2b(x0[0]) | ((unsigned int)f2b(x0[1]) << 16),
            (unsigned int)f2b(x0[2]) | ((unsigned int)f2b(x0[3]) << 16),
            (unsigned int)f2b(x1[0]) | ((unsigned int)f2b(x1[1]) << 16),
            (unsigned int)f2b(x1[2]) | ((unsigned int)f2b(x1[3]) << 16),
            (unsigned int)f2b(x2[0]) | ((unsigned int)f2b(x2[1]) << 16),
            (unsigned int)f2b(x2[2]) | ((unsigned int)f2b(x2[3]) << 16),
            (unsigned int)f2b(x3[0]) | ((unsigned int)f2b(x3[1]) << 16),
            (unsigned int)f2b(x3[2]) | ((unsigned int)f2b(x3[3]) << 16) };
        bf16x8 af0 = __builtin_bit_cast(bf16x8, make_uint4(pk[0], pk[1], pk[2], pk[3]));
        bf16x8 af1 = __builtin_bit_cast(bf16x8, make_uint4(pk[4], pk[5], pk[6], pk[7]));

        // MFMA with current (prefetched) B-frags
        acc0 = __builtin_amdgcn_mfma_f32_16x16x32_bf16(af0, __builtin_bit_cast(bf16x8, B00), acc0, 0, 0, 0);
        acc1 = __builtin_amdgcn_mfma_f32_16x16x32_bf16(af0, __builtin_bit_cast(bf16x8, B10), acc1, 0, 0, 0);
        acc0 = __builtin_amdgcn_mfma_f32_16x16x32_bf16(af1, __builtin_bit_cast(bf16x8, B01), acc0, 0, 0, 0);
        acc1 = __builtin_amdgcn_mfma_f32_16x16x32_bf16(af1, __builtin_bit_cast(bf16x8, B11), acc1, 0, 0, 0);

        // alpha fp32 out — after MFMA so store drain decouples from load wait
        *(f32x4*)(o1 + mA)      = x0;
        *(f32x4*)(o1 + mA + 4)  = x1;
        *(f32x4*)(o1 + mA + 32) = x2;
        *(f32x4*)(o1 + mA + 36) = x3;

        if (c < 7) { B00 = N00; B01 = N01; B10 = N10; B11 = N11; }
    }

    // ---- cross-wave C reduction + relu epilogue (Cred overlays Es/bits) ----
    __syncthreads();   // all waves done reading Es/bits before overlay write
#pragma unroll
    for (int i = 0; i < 4; i++) {
        Cred[w][(quad << 2) + i][l16]      = acc0[i];
        Cred[w][(quad << 2) + i][l16 + 16] = acc1[i];
    }
    __syncthreads();
#pragma unroll
    for (int e = t; e < 512; e += 256) {
        const int r = e >> 5, d = e & 31;
        float v = Cred[0][r][d] + Cred[1][r][d] + Cred[2][r][d] + Cred[3][r][d];
        out0[((size_t)(b * NN + n0 + r)) * (HH * DOUT) + h * DOUT + d] = fmaxf(v, 0.f);
    }
}

// ---------------------------------------------------------------------------
extern "C" void kernel_launch(void* const* d_in, const int* in_sizes, int n_in,
                              void* d_out, int out_size, void* d_ws, size_t ws_size,
                              hipStream_t stream)
{
    const float* Hg  = (const float*)d_in[0];
    const int*   adj = (const int*)d_in[1];
    const float* Wg  = (const float*)d_in[2];
    const float* ag  = (const float*)d_in[3];

    float* out0 = (float*)d_out;
    float* out1 = out0 + (size_t)BB * NN * HH * DOUT;   // alpha after h'

    char* ws = (char*)d_ws;
    unsigned short* WhT = (unsigned short*)ws;                                // 4 MB bf16
    float*          E   = (float*)(ws + (size_t)BB*HH*DOUT*NN*2);             // 256 KB
    unsigned int*   BM  = (unsigned int*)(ws + (size_t)BB*HH*DOUT*NN*2
                                             + (size_t)BB*HH*NN*4);           // 2 MB

    k_wht <<<BB * (NN/16),          256, 0, stream>>>(Hg, Wg, ag, WhT, E);
    k_bits<<<(BB * NN * NN) / 4096, 256, 0, stream>>>(adj, (unsigned long long*)BM);
    k_main<<<BB * HH * (NN/16),     256, 0, stream>>>(E, BM, WhT, out0, out1);
}